// Round 10
// baseline (188.023 us; speedup 1.0000x reference)
//
#include <hip/hip_runtime.h>
#include <math.h>

#define DDIM 4096
#define EDIM 64
#define NROWS 16384
#define MBLK 32
#define NKT 64            // K-tiles of 64
#define TOPK_K 8
#define DIGIT_BIAS 0x00808080

typedef int i32x4 __attribute__((ext_vector_type(4)));

// signed-digit int8 decomposition: bytes of (v+BIAS)^BIAS are signed digits
// d_p with v = sum d_p * 256^p (exact for |v| < 2^31 - 2^23)
__device__ __forceinline__ int digits_rn(float f) {
  int v = __float2int_rn(f);
  return (v + DIGIT_BIAS) ^ DIGIT_BIAS;
}
__device__ __forceinline__ int digits_tz(float f) {
  int v = (int)f;                    // trunc cvt; noise ~1e-8 (verified R9)
  return (v + DIGIT_BIAS) ^ DIGIT_BIAS;
}

__device__ __forceinline__ unsigned perm_b32(unsigned a, unsigned b, unsigned sel) {
#if __has_builtin(__builtin_amdgcn_perm)
  return __builtin_amdgcn_perm(a, b, sel);
#else
  union { unsigned u[2]; unsigned char c[8]; } s; s.u[0] = b; s.u[1] = a;
  unsigned r = 0;
  for (int i = 0; i < 4; ++i) r |= (unsigned)s.c[(sel >> (8*i)) & 7] << (8*i);
  return r;
#endif
}

// ---------------------------------------------------------------------------
// Wr [4096][64] f32 -> 4 int8 digit planes (w*2^36), fragment-major,
// 64-K-tile granular. (verified R4-R9: idx exact) — UNCHANGED
// ---------------------------------------------------------------------------
__global__ __launch_bounds__(256) void wr_convert(const float* __restrict__ Wr,
                                                  char* __restrict__ wl8) {
  int t = blockIdx.x * 256 + threadIdx.x;
  int e = t & 63, k16 = t >> 6;
  int kt64 = k16 >> 2, kgg = k16 & 3, nf = e >> 4, col = e & 15;
  int D[16];
  #pragma unroll
  for (int j = 0; j < 16; ++j)
    D[j] = digits_rn(Wr[(size_t)(k16 * 16 + j) * EDIM + e] * 68719476736.0f);
  #pragma unroll
  for (int pl = 0; pl < 4; ++pl) {
    unsigned wv[4];
    #pragma unroll
    for (int g = 0; g < 4; ++g)
      wv[g] = ((unsigned)((D[4*g+0] >> (8*pl)) & 255))
            | ((unsigned)((D[4*g+1] >> (8*pl)) & 255) << 8)
            | ((unsigned)((D[4*g+2] >> (8*pl)) & 255) << 16)
            | ((unsigned)((D[4*g+3] >> (8*pl)) & 255) << 24);
    i32x4 val = {(int)wv[0], (int)wv[1], (int)wv[2], (int)wv[3]};
    *(i32x4*)(wl8 + (size_t)pl * 262144 + (size_t)(kt64 * 4 + nf) * 1024
              + (size_t)(kgg * 16 + col) * 16) = val;
  }
}

// ---------------------------------------------------------------------------
// Fused exact router — NO LDS / NO BARRIERS in the main loop. All operands
// loaded straight to VGPRs (x coalesced per-lane 64B; W frags contiguous
// 1KiB wave-chunks, L2-resident). 2-tile register lookahead; waves slip
// freely so VALU/MFMA/VMEM overlap via 4-wave/SIMD TLP.
// 512 blocks x 512 threads; 32 rows/block; 8 waves = 2mw x 4nw.
// ---------------------------------------------------------------------------
__global__ __launch_bounds__(512, 4) void router_fused(
    const float* __restrict__ x, const char* __restrict__ wl8,
    const float* __restrict__ br,
    float* __restrict__ out_scores, float* __restrict__ out_idx) {
  __shared__ double ls[MBLK * EDIM];   // 16 KiB, epilogue only

  const int tid  = threadIdx.x;
  const int lane = tid & 63;
  const int w    = tid >> 6;
  const int mw   = w >> 2;
  const int nw   = w & 3;
  const int kg   = lane >> 4;
  const int row0 = blockIdx.x * MBLK;
  const int row_l = mw * 16 + (lane & 15);
  const float bias = br[nw * 16 + (lane & 15)];

  // lane-invariant bases: x k-offset (lane's own row + kg slot), W frag chunk
  const char* xr = (const char*)x + ((size_t)(row0 + row_l)) * (DDIM * 4) + kg * 64;
  const char* wr = wl8 + (size_t)nw * 1024 + (size_t)lane * 16;

  i32x4 acc[5] = {};                // digit-weight classes s6..s2
  float4 X0[4], X1[4];
  i32x4  B0[4], B1[4];
  i32x4  A[4];

  auto loadX = [&](int t, float4 (&X)[4]) {
    const char* p = xr + t * 256;
    #pragma unroll
    for (int c = 0; c < 4; ++c) X[c] = *(const float4*)(p + c * 16);
  };
  auto loadB = [&](int t, i32x4 (&B)[4]) {
    const char* p = wr + (size_t)t * 4096;
    #pragma unroll
    for (int pl = 0; pl < 4; ++pl)
      B[pl] = *(const i32x4*)(p + (size_t)pl * 262144);
  };
  auto cvtg = [&](const float4& v, int g) {
    unsigned f0 = (unsigned)digits_tz(v.x * 33554432.0f);   // x * 2^25
    unsigned f1 = (unsigned)digits_tz(v.y * 33554432.0f);
    unsigned f2 = (unsigned)digits_tz(v.z * 33554432.0f);
    unsigned f3 = (unsigned)digits_tz(v.w * 33554432.0f);
    unsigned zl01 = perm_b32(f1, f0, 0x05010400u);
    unsigned zh01 = perm_b32(f1, f0, 0x07030602u);
    unsigned zl23 = perm_b32(f3, f2, 0x05010400u);
    unsigned zh23 = perm_b32(f3, f2, 0x07030602u);
    A[0][g] = (int)perm_b32(zl23, zl01, 0x05040100u);
    A[1][g] = (int)perm_b32(zl23, zl01, 0x07060302u);
    A[2][g] = (int)perm_b32(zh23, zh01, 0x05040100u);
    A[3][g] = (int)perm_b32(zh23, zh01, 0x07060302u);
  };
  // 13 MFMAs, round-robin across acc classes (pure int reassociation: exact)
  auto mfmaAll = [&](i32x4 (&b)[4]) {
    acc[0] = __builtin_amdgcn_mfma_i32_16x16x64_i8(A[3], b[3], acc[0], 0, 0, 0);
    acc[1] = __builtin_amdgcn_mfma_i32_16x16x64_i8(A[3], b[2], acc[1], 0, 0, 0);
    acc[2] = __builtin_amdgcn_mfma_i32_16x16x64_i8(A[3], b[1], acc[2], 0, 0, 0);
    acc[3] = __builtin_amdgcn_mfma_i32_16x16x64_i8(A[3], b[0], acc[3], 0, 0, 0);
    acc[4] = __builtin_amdgcn_mfma_i32_16x16x64_i8(A[2], b[0], acc[4], 0, 0, 0);
    acc[1] = __builtin_amdgcn_mfma_i32_16x16x64_i8(A[2], b[3], acc[1], 0, 0, 0);
    acc[2] = __builtin_amdgcn_mfma_i32_16x16x64_i8(A[2], b[2], acc[2], 0, 0, 0);
    acc[3] = __builtin_amdgcn_mfma_i32_16x16x64_i8(A[2], b[1], acc[3], 0, 0, 0);
    acc[4] = __builtin_amdgcn_mfma_i32_16x16x64_i8(A[1], b[1], acc[4], 0, 0, 0);
    acc[2] = __builtin_amdgcn_mfma_i32_16x16x64_i8(A[1], b[3], acc[2], 0, 0, 0);
    acc[3] = __builtin_amdgcn_mfma_i32_16x16x64_i8(A[1], b[2], acc[3], 0, 0, 0);
    acc[4] = __builtin_amdgcn_mfma_i32_16x16x64_i8(A[0], b[2], acc[4], 0, 0, 0);
    acc[3] = __builtin_amdgcn_mfma_i32_16x16x64_i8(A[0], b[3], acc[3], 0, 0, 0);
  };

  // prologue: 2 tiles in flight
  loadB(0, B0); loadX(0, X0);
  loadB(1, B1); loadX(1, X1);

  for (int t = 0; t < NKT; t += 2) {
    cvtg(X0[0], 0); cvtg(X0[1], 1); cvtg(X0[2], 2); cvtg(X0[3], 3);
    mfmaAll(B0);
    if (t + 2 < NKT) { loadB(t + 2, B0); loadX(t + 2, X0); }
    cvtg(X1[0], 0); cvtg(X1[1], 1); cvtg(X1[2], 2); cvtg(X1[3], 3);
    mfmaAll(B1);
    if (t + 3 < NKT) { loadB(t + 3, B1); loadX(t + 3, X1); }
  }

  // ---- epilogue: fp64 combine (class s: 2^(8s-61)), top-8, sparse softmax ----
  {
    int cc = nw * 16 + (lane & 15);
    #pragma unroll
    for (int j = 0; j < 4; ++j) {
      int r = mw * 16 + (lane >> 4) * 4 + j;   // C/D: row=(lane>>4)*4+reg
      double lg = (double)acc[0][j] * 0x1p-13 + (double)acc[1][j] * 0x1p-21
                + (double)acc[2][j] * 0x1p-29 + (double)acc[3][j] * 0x1p-37
                + (double)acc[4][j] * 0x1p-45 + (double)bias;
      ls[r * 64 + cc] = lg;
    }
  }
  __syncthreads();

  for (int rr = 0; rr < 4; ++rr) {
    int r = w * 4 + rr;
    double v0 = ls[r * 64 + lane];
    double cur = v0;
    bool sel  = false;
    int myidx = 0;
    double maxv = 0.0;
    #pragma unroll
    for (int k = 0; k < TOPK_K; ++k) {
      double bv = cur;
      int    bi = lane;
      #pragma unroll
      for (int off = 32; off; off >>= 1) {
        double ov = __shfl_xor(bv, off);
        int    oi = __shfl_xor(bi, off);
        if (ov > bv || (ov == bv && oi < bi)) { bv = ov; bi = oi; }
      }
      if (k == 0) maxv = bv;
      if (lane == k) myidx = bi;
      if (lane == bi) { cur = -__builtin_inf(); sel = true; }
    }
    float pv = sel ? expf((float)(v0 - maxv)) : 0.f;
    float ssum = pv;
    #pragma unroll
    for (int off = 32; off; off >>= 1) ssum += __shfl_xor(ssum, off);

    size_t rg = (size_t)row0 + r;
    out_scores[rg * 64 + lane] = pv / ssum;
    if (lane < TOPK_K) out_idx[rg * 8 + lane] = (float)myidx;
  }
}

extern "C" void kernel_launch(void* const* d_in, const int* in_sizes, int n_in,
                              void* d_out, int out_size, void* d_ws, size_t ws_size,
                              hipStream_t stream) {
  const float* x  = (const float*)d_in[0];
  const float* Wr = (const float*)d_in[1];
  const float* br = (const float*)d_in[2];
  // d_in[3] (Wn), d_in[4] (bn): dead code in the reference — intentionally unused.

  char* wl8 = (char*)d_ws;                          // 4 planes x 256 KiB = 1 MiB
  float* out_scores = (float*)d_out;
  float* out_idx    = out_scores + (size_t)NROWS * EDIM;

  wr_convert<<<64, 256, 0, stream>>>(Wr, wl8);
  router_fused<<<NROWS / MBLK, 512, 0, stream>>>(x, wl8, br, out_scores, out_idx);
}

// Round 13
// 178.047 us; speedup vs baseline: 1.0560x; 1.0560x over previous
//
#include <hip/hip_runtime.h>
#include <math.h>

#define DDIM 4096
#define EDIM 64
#define NROWS 16384
#define MBLK 64
#define TOPK_K 8
#define DIGIT_BIAS 0x00808080

typedef int   i32x4  __attribute__((ext_vector_type(4)));
typedef int   i32x16 __attribute__((ext_vector_type(16)));

// signed-digit int8 decomposition: bytes of (v+BIAS)^BIAS are signed digits
// d_p with v = sum d_p * 256^p (exact for |v| < 2^31 - 2^23)
__device__ __forceinline__ int digits_rn(float f) {
  int v = __float2int_rn(f);
  return (v + DIGIT_BIAS) ^ DIGIT_BIAS;
}
__device__ __forceinline__ int digits_tz(float f) {
  int v = (int)f;                    // trunc cvt; verified R9/R10
  return (v + DIGIT_BIAS) ^ DIGIT_BIAS;
}

__device__ __forceinline__ unsigned perm_b32(unsigned a, unsigned b, unsigned sel) {
#if __has_builtin(__builtin_amdgcn_perm)
  return __builtin_amdgcn_perm(a, b, sel);
#else
  union { unsigned u[2]; unsigned char c[8]; } s; s.u[0] = b; s.u[1] = a;
  unsigned r = 0;
  for (int i = 0; i < 4; ++i) r |= (unsigned)s.c[(sel >> (8*i)) & 7] << (8*i);
  return r;
#endif
}

// convert 4 f32 (group g) -> byte-group g of 4 digit-plane regs (x * 2^25)
__device__ __forceinline__ void cvtg(const float4& v, i32x4 (&An)[4], int g) {
  unsigned f0 = (unsigned)digits_tz(v.x * 33554432.0f);
  unsigned f1 = (unsigned)digits_tz(v.y * 33554432.0f);
  unsigned f2 = (unsigned)digits_tz(v.z * 33554432.0f);
  unsigned f3 = (unsigned)digits_tz(v.w * 33554432.0f);
  unsigned zl01 = perm_b32(f1, f0, 0x05010400u);
  unsigned zh01 = perm_b32(f1, f0, 0x07030602u);
  unsigned zl23 = perm_b32(f3, f2, 0x05010400u);
  unsigned zh23 = perm_b32(f3, f2, 0x07030602u);
  An[0][g] = (int)perm_b32(zl23, zl01, 0x05040100u);
  An[1][g] = (int)perm_b32(zl23, zl01, 0x07060302u);
  An[2][g] = (int)perm_b32(zh23, zh01, 0x05040100u);
  An[3][g] = (int)perm_b32(zh23, zh01, 0x07060302u);
}

// ---------------------------------------------------------------------------
// Wr [4096][64] f32 -> 4 int8 digit planes (w*2^36), 32x32 B-fragment layout:
// frag (kt32 = k>>5, nf32 = e>>5), 1 KiB/plane/frag; lane = (khalf<<5)|(e&31)
// holds bytes j=0..15 = digits of k = kt32*32 + khalf*16 + j  (canonical map,
// same map used on the A side so any HW k-permutation cancels).
// ---------------------------------------------------------------------------
__global__ __launch_bounds__(256) void wr_convert32(const float* __restrict__ Wr,
                                                    char* __restrict__ wl8) {
  int t = blockIdx.x * 256 + threadIdx.x;      // 16384 threads
  int e = t & 63, k16 = t >> 6;                // 16 consecutive k per thread
  int frag = (k16 >> 1) * 2 + (e >> 5);
  int ln   = (k16 & 1) * 32 + (e & 31);
  int D[16];
  #pragma unroll
  for (int j = 0; j < 16; ++j)
    D[j] = digits_rn(Wr[(size_t)(k16 * 16 + j) * EDIM + e] * 68719476736.0f); // 2^36
  #pragma unroll
  for (int pl = 0; pl < 4; ++pl) {
    unsigned wv[4];
    #pragma unroll
    for (int g = 0; g < 4; ++g)
      wv[g] = ((unsigned)((D[4*g+0] >> (8*pl)) & 255))
            | ((unsigned)((D[4*g+1] >> (8*pl)) & 255) << 8)
            | ((unsigned)((D[4*g+2] >> (8*pl)) & 255) << 16)
            | ((unsigned)((D[4*g+3] >> (8*pl)) & 255) << 24);
    i32x4 val = {(int)wv[0], (int)wv[1], (int)wv[2], (int)wv[3]};
    *(i32x4*)(wl8 + (size_t)pl * 262144 + (size_t)frag * 1024
              + (size_t)ln * 16) = val;
  }
}

// ---------------------------------------------------------------------------
// Fused exact router on 32x32x32 i8 MFMA (4x arithmetic intensity per
// operand byte vs 16x16x64). Grid 256 x 512 (1 block/CU), MBLK=64.
// Waves: mw(2) x nv(2) x kw(2); wave = 32 rows x 32 experts x 2048 k.
// W staged via global_load_lds double-buffer; x direct per-lane loads.
// Single __syncthreads per iteration (m97 structure). kw-partials combined
// exactly in i32 via LDS; fp64 logits; verified top-8 epilogue.
// ---------------------------------------------------------------------------
__global__ __launch_bounds__(512, 2) void router_fused(
    const float* __restrict__ x, const char* __restrict__ wl8,
    const float* __restrict__ br,
    float* __restrict__ out_scores, float* __restrict__ out_idx) {
  __shared__ __align__(16) char smem[32768];  // loop: 2kw x 2buf x 8KB; epi reuse

  const int tid  = threadIdx.x;
  const int lane = tid & 63;
  const int w    = tid >> 6;
  const int mw   = w >> 2;            // 32-row band
  const int nv   = (w >> 1) & 1;      // 32-expert band
  const int kw   = w & 1;             // k-half (64 subtiles of 32)
  const int row0 = blockIdx.x * MBLK;

  // x: lane reads its own row, 64B per subtile (16 floats at khalf*16)
  const char* xb = (const char*)x
      + (size_t)(row0 + mw * 32 + (lane & 31)) * (DDIM * 4)
      + (size_t)((lane >> 5) * 64);

  // W staging: this wave's 2 chunks (of 8 = 4 planes x 2 nf per kw-group)
  const int c0 = (mw * 2 + nv) * 2, c1 = c0 + 1;
  const char* wsrc0 = wl8 + (size_t)(c0 >> 1) * 262144 + (size_t)(c0 & 1) * 1024
                          + (size_t)lane * 16;
  const char* wsrc1 = wl8 + (size_t)(c1 >> 1) * 262144 + (size_t)(c1 & 1) * 1024
                          + (size_t)lane * 16;
  char* wdst0 = smem + kw * 16384 + (c0 >> 1) * 2048 + (c0 & 1) * 1024;
  char* wdst1 = smem + kw * 16384 + (c1 >> 1) * 2048 + (c1 & 1) * 1024;

  i32x16 s6{}, s5{}, s4{}, s3{}, s2{};   // digit-weight classes (i32 exact)

  auto gll = [](const char* src, char* dst) {
    __builtin_amdgcn_global_load_lds(
        (const __attribute__((address_space(1))) unsigned int*)(const void*)src,
        (__attribute__((address_space(3))) unsigned int*)(void*)dst, 16, 0, 0);
  };
  auto stage = [&](int i, int d) {        // subtile s = kw*64+i -> frag s*2+nf
    size_t so = (size_t)(kw * 64 + i) * 2048;
    gll(wsrc0 + so, wdst0 + d * 8192);
    gll(wsrc1 + so, wdst1 + d * 8192);
  };

  stage(0, 0);
  __syncthreads();
  for (int i = 0; i < 64; ++i) {
    const int cur = i & 1;
    if (i + 1 < 64) stage(i + 1, cur ^ 1);

    // x -> A digit planes (x * 2^25)
    const char* xp = xb + (size_t)(kw * 64 + i) * 128;
    float4 x0 = *(const float4*)(xp);
    float4 x1 = *(const float4*)(xp + 16);
    float4 x2 = *(const float4*)(xp + 32);
    float4 x3 = *(const float4*)(xp + 48);
    i32x4 A[4];
    cvtg(x0, A, 0); cvtg(x1, A, 1); cvtg(x2, A, 2); cvtg(x3, A, 3);

    // B digit planes from LDS (this wave's nf = nv)
    const char* Bb = smem + kw * 16384 + cur * 8192 + nv * 1024 + (size_t)lane * 16;
    i32x4 b0 = *(const i32x4*)(Bb);
    i32x4 b1 = *(const i32x4*)(Bb + 2048);
    i32x4 b2 = *(const i32x4*)(Bb + 4096);
    i32x4 b3 = *(const i32x4*)(Bb + 6144);

    // 13 MFMAs: classes s = i+j >= 2 (weights 2^(8s-61))
    s6 = __builtin_amdgcn_mfma_i32_32x32x32_i8(A[3], b3, s6, 0, 0, 0);
    s5 = __builtin_amdgcn_mfma_i32_32x32x32_i8(A[3], b2, s5, 0, 0, 0);
    s5 = __builtin_amdgcn_mfma_i32_32x32x32_i8(A[2], b3, s5, 0, 0, 0);
    s4 = __builtin_amdgcn_mfma_i32_32x32x32_i8(A[3], b1, s4, 0, 0, 0);
    s4 = __builtin_amdgcn_mfma_i32_32x32x32_i8(A[2], b2, s4, 0, 0, 0);
    s4 = __builtin_amdgcn_mfma_i32_32x32x32_i8(A[1], b3, s4, 0, 0, 0);
    s3 = __builtin_amdgcn_mfma_i32_32x32x32_i8(A[3], b0, s3, 0, 0, 0);
    s3 = __builtin_amdgcn_mfma_i32_32x32x32_i8(A[2], b1, s3, 0, 0, 0);
    s3 = __builtin_amdgcn_mfma_i32_32x32x32_i8(A[1], b2, s3, 0, 0, 0);
    s3 = __builtin_amdgcn_mfma_i32_32x32x32_i8(A[0], b3, s3, 0, 0, 0);
    s2 = __builtin_amdgcn_mfma_i32_32x32x32_i8(A[2], b0, s2, 0, 0, 0);
    s2 = __builtin_amdgcn_mfma_i32_32x32x32_i8(A[1], b1, s2, 0, 0, 0);
    s2 = __builtin_amdgcn_mfma_i32_32x32x32_i8(A[0], b2, s2, 0, 0, 0);
    __syncthreads();
  }

  // ---- kw-combine: kw=1 partials added into kw=0 accs (i32, exact) ----
  const unsigned cb = (unsigned)((mw * 2 + nv) * 4096 + lane * 64);
#define CROUND(ACC) do {                                    \
    if (kw == 1) {                                          \
      _Pragma("unroll")                                     \
      for (int e2 = 0; e2 < 16; ++e2)                       \
        ((int*)(smem + cb))[e2] = ACC[e2];                  \
    }                                                       \
    __syncthreads();                                        \
    if (kw == 0) {                                          \
      _Pragma("unroll")                                     \
      for (int e2 = 0; e2 < 16; ++e2)                       \
        ACC[e2] += ((const int*)(smem + cb))[e2];           \
    }                                                       \
    __syncthreads();                                        \
  } while (0)
  CROUND(s6); CROUND(s5); CROUND(s4); CROUND(s3); CROUND(s2);

  // ---- fp64 logits (32x32 C/D: col=lane&31, row=(r&3)+8*(r>>2)+4*(l>>5)) ----
  double* ls = (double*)smem;           // 64 x 64 doubles = 32 KiB
  if (kw == 0) {
    const float bias = br[nv * 32 + (lane & 31)];
    const int col = nv * 32 + (lane & 31);
    #pragma unroll
    for (int r = 0; r < 16; ++r) {
      int row = mw * 32 + (r & 3) + 8 * (r >> 2) + 4 * (lane >> 5);
      ls[row * 64 + col] = (double)s6[r] * 0x1p-13 + (double)s5[r] * 0x1p-21
                         + (double)s4[r] * 0x1p-29 + (double)s3[r] * 0x1p-37
                         + (double)s2[r] * 0x1p-45 + (double)bias;
    }
  }
  __syncthreads();

  // ---- top-8 (fp64 exact) + sparse softmax: 8 waves x 8 rows (verified) ----
  for (int rr = 0; rr < 8; ++rr) {
    int r = w * 8 + rr;
    double v0 = ls[r * 64 + lane];
    double cur = v0;
    bool sel  = false;
    int myidx = 0;
    double maxv = 0.0;
    #pragma unroll
    for (int k = 0; k < TOPK_K; ++k) {
      double bv = cur;
      int    bi = lane;
      #pragma unroll
      for (int off = 32; off; off >>= 1) {
        double ov = __shfl_xor(bv, off);
        int    oi = __shfl_xor(bi, off);
        if (ov > bv || (ov == bv && oi < bi)) { bv = ov; bi = oi; }
      }
      if (k == 0) maxv = bv;
      if (lane == k) myidx = bi;
      if (lane == bi) { cur = -__builtin_inf(); sel = true; }
    }
    float pv = sel ? expf((float)(v0 - maxv)) : 0.f;
    float ssum = pv;
    #pragma unroll
    for (int off = 32; off; off >>= 1) ssum += __shfl_xor(ssum, off);

    size_t rg = (size_t)row0 + r;
    out_scores[rg * 64 + lane] = pv / ssum;
    if (lane < TOPK_K) out_idx[rg * 8 + lane] = (float)myidx;
  }
}

extern "C" void kernel_launch(void* const* d_in, const int* in_sizes, int n_in,
                              void* d_out, int out_size, void* d_ws, size_t ws_size,
                              hipStream_t stream) {
  const float* x  = (const float*)d_in[0];
  const float* Wr = (const float*)d_in[1];
  const float* br = (const float*)d_in[2];
  // d_in[3] (Wn), d_in[4] (bn): dead code in the reference — intentionally unused.

  char* wl8 = (char*)d_ws;                          // 4 planes x 256 KiB = 1 MiB
  float* out_scores = (float*)d_out;
  float* out_idx    = out_scores + (size_t)NROWS * EDIM;

  wr_convert32<<<64, 256, 0, stream>>>(Wr, wl8);
  router_fused<<<NROWS / MBLK, 512, 0, stream>>>(x, wl8, br, out_scores, out_idx);
}